// Round 15
// baseline (232.796 us; speedup 1.0000x reference)
//
#include <hip/hip_runtime.h>

typedef __bf16 bf16;
typedef __attribute__((ext_vector_type(8))) __bf16 bf16x8;
typedef __attribute__((ext_vector_type(4))) float f32x4;
typedef __attribute__((ext_vector_type(16))) float f32x16;
typedef unsigned int u32;

#define MFMA16(a, b, c) __builtin_amdgcn_mfma_f32_16x16x32_bf16((a), (b), (c), 0, 0, 0)
#define MFMA32(a, b, c) __builtin_amdgcn_mfma_f32_32x32x16_bf16((a), (b), (c), 0, 0, 0)

// Problem constants
#define BB 2
#define SS 2048
#define EE 1024
#define HH 16
#define DD 64
#define MM (BB * SS)  // 4096

__device__ inline f32x4 zero4() {
    f32x4 z; z.x = 0.f; z.y = 0.f; z.z = 0.f; z.w = 0.f; return z;
}

// async global->LDS DMA, 16B per lane.  LDS dest = wave-uniform base + lane*16.
__device__ __forceinline__ void gload16(const bf16* g, bf16* l) {
    __builtin_amdgcn_global_load_lds(
        (const __attribute__((address_space(1))) u32*)(const void*)g,
        (__attribute__((address_space(3))) u32*)(void*)l,
        16, 0, 0);
}

__device__ __forceinline__ u32 pkbf(float a, float b) {
    union { __bf16 h; unsigned short s; } ua, ub;
    ua.h = (__bf16)a; ub.h = (__bf16)b;
    return (u32)ua.s | ((u32)ub.s << 16);
}

// ---------------------------------------------------------------------------
// Kernel 1: fused prep (unchanged).
// ---------------------------------------------------------------------------
__global__ __launch_bounds__(256) void prep_kernel(
    const float* __restrict__ query, bf16* __restrict__ qc,
    const float* __restrict__ s0, const float* __restrict__ s1,
    const float* __restrict__ s2, const float* __restrict__ s3,
    bf16* __restrict__ d0, bf16* __restrict__ d1,
    bf16* __restrict__ d2, bf16* __restrict__ d3,
    const float* __restrict__ xi, const float* __restrict__ w1,
    const float* __restrict__ b1, const float* __restrict__ lng,
    const float* __restrict__ lnb, const float* __restrict__ w2,
    const float* __restrict__ b2, const float* __restrict__ gate,
    float* __restrict__ adapt) {
    __shared__ bf16 tile[64 * 72];
    const int bid = blockIdx.x;
    const int t = threadIdx.x;

    if (bid < 2048) {
        const int i = (bid * 256 + t) * 8;
        float4 a = *(const float4*)(query + i);
        float4 b = *(const float4*)(query + i + 4);
        bf16 tmp[8];
        tmp[0] = (bf16)a.x; tmp[1] = (bf16)a.y; tmp[2] = (bf16)a.z; tmp[3] = (bf16)a.w;
        tmp[4] = (bf16)b.x; tmp[5] = (bf16)b.y; tmp[6] = (bf16)b.z; tmp[7] = (bf16)b.w;
        *(uint4*)(qc + i) = *(uint4*)tmp;
    } else if (bid < 3072) {
        const int m = (bid - 2048) >> 8;
        const int idx0 = (bid - 2048) & 255;
        const float* W = (m == 0) ? s0 : (m == 1) ? s1 : (m == 2) ? s2 : s3;
        bf16* Wt = (m == 0) ? d0 : (m == 1) ? d1 : (m == 2) ? d2 : d3;
        const int k0 = (idx0 >> 4) * 64, n0 = (idx0 & 15) * 64;
#pragma unroll
        for (int i = 0; i < 2; ++i) {
            int idx = i * 256 + t;
            int r = idx >> 3, c = (idx & 7) * 8;
            float4 a = *(const float4*)(W + (k0 + r) * EE + n0 + c);
            float4 b = *(const float4*)(W + (k0 + r) * EE + n0 + c + 4);
            bf16 tmp[8];
            tmp[0] = (bf16)a.x; tmp[1] = (bf16)a.y; tmp[2] = (bf16)a.z; tmp[3] = (bf16)a.w;
            tmp[4] = (bf16)b.x; tmp[5] = (bf16)b.y; tmp[6] = (bf16)b.z; tmp[7] = (bf16)b.w;
            *(uint4*)(tile + r * 72 + c) = *(uint4*)tmp;
        }
        __syncthreads();
#pragma unroll
        for (int i = 0; i < 2; ++i) {
            int idx = i * 256 + t;
            int n = idx >> 3, kc = (idx & 7) * 8;
            bf16 tmp[8];
#pragma unroll
            for (int j = 0; j < 8; ++j) tmp[j] = tile[(kc + j) * 72 + n];
            *(uint4*)(Wt + (n0 + n) * EE + k0 + kc) = *(uint4*)tmp;
        }
    } else {
        const int b = bid - 3072;
        float* xs = (float*)tile;
        if (t < 64) {
            const float xiv = xi[b];
            float xv = 0.f;
            if (t < 32) xv = xiv * w1[t] + b1[t];
            float sm = xv;
            for (int off = 1; off < 32; off <<= 1) sm += __shfl_xor(sm, off);
            const float mu = sm * (1.f / 32.f);
            float dv = (t < 32) ? (xv - mu) : 0.f;
            float s2 = dv * dv;
            for (int off = 1; off < 32; off <<= 1) s2 += __shfl_xor(s2, off);
            const float var = s2 * (1.f / 32.f);
            if (t < 32) {
                float xn = (xv - mu) * rsqrtf(var + 1e-5f) * lng[t] + lnb[t];
                float ge = 0.5f * xn * (1.f + erff(xn * 0.70710678118654752f));
                xs[t] = ge;
            }
        }
        __syncthreads();
        if (t < 64) {
            float acc = b2[t];
            for (int j = 0; j < 32; ++j) acc += xs[j] * w2[j * DD + t];
            for (int h = 0; h < HH; ++h) {
                float sg = 1.f / (1.f + __expf(-gate[h]));
                adapt[(b * HH + h) * DD + t] = 1.f + sg * acc;
            }
        }
    }
}

// ---------------------------------------------------------------------------
// Kernel 2: QKV GEMM — 128x128 tile, BK=32, dbuf DMA, one barrier/iter.
// q-scale folds 0.125*log2(e) so attention uses bare v_exp_f32 (exp2).
// ---------------------------------------------------------------------------
__global__ __launch_bounds__(256, 3) void gemm_qkv(
    const bf16* __restrict__ Aq, const bf16* __restrict__ Bqk,
    const bf16* __restrict__ Av,
    const float* __restrict__ bias, const float* __restrict__ bias2,
    const float* __restrict__ bias3, const float* __restrict__ adapt,
    bf16* __restrict__ outqk, bf16* __restrict__ outvt) {
    __shared__ bf16 As[2 * 128 * 32];
    __shared__ bf16 Bs[2 * 128 * 32];

    const int t = threadIdx.x;
    const int w = t >> 6, lane = t & 63;
    const int mrow = lane & 15, quad = lane >> 4;
    const int wm = (w & 1) * 64, wn = (w >> 1) * 64;

    int md, bx, by;
    const bf16 *Ap, *Bp;
    int bid = blockIdx.x;
    if (bid < 512) { md = 5; bx = bid & 31; by = bid >> 5; Ap = Aq; Bp = Bqk; }
    else { md = 4; bid -= 512; bx = bid & 7; by = bid >> 3; Ap = Av; Bp = Aq; }
    const int m0 = bx * 128, n0 = by * 128;

    f32x4 acc[4][4];
#pragma unroll
    for (int i = 0; i < 4; ++i)
#pragma unroll
        for (int j = 0; j < 4; ++j) acc[i][j] = zero4();

    const int dr = lane >> 2;
    const int dcg = ((lane & 3) ^ (dr & 3)) * 8;
    const bf16* Ag = Ap + (size_t)(m0 + w * 16 + dr) * EE + dcg;
    const bf16* Bg = Bp + (size_t)(n0 + w * 16 + dr) * EE + dcg;
    bf16* Al = As + (w * 16) * 32;
    bf16* Bl = Bs + (w * 16) * 32;

    gload16(Ag, Al);
    gload16(Ag + 64 * EE, Al + 64 * 32);
    gload16(Bg, Bl);
    gload16(Bg + 64 * EE, Bl + 64 * 32);

    for (int kt = 0; kt < 32; ++kt) {
        __syncthreads();
        if (kt < 31) {
            const int kn = (kt + 1) * 32;
            const int nb = (kt + 1) & 1;
            gload16(Ag + kn, Al + nb * 4096);
            gload16(Ag + 64 * EE + kn, Al + nb * 4096 + 64 * 32);
            gload16(Bg + kn, Bl + nb * 4096);
            gload16(Bg + 64 * EE + kn, Bl + nb * 4096 + 64 * 32);
        }
        const bf16* Ab = As + (kt & 1) * 4096;
        const bf16* Bb = Bs + (kt & 1) * 4096;
        const int sw = (quad ^ (mrow & 3)) * 8;
        bf16x8 af[4], bfr[4];
#pragma unroll
        for (int i = 0; i < 4; ++i)
            af[i] = *(const bf16x8*)(Ab + (wm + i * 16 + mrow) * 32 + sw);
#pragma unroll
        for (int j = 0; j < 4; ++j)
            bfr[j] = *(const bf16x8*)(Bb + (wn + j * 16 + mrow) * 32 + sw);
#pragma unroll
        for (int i = 0; i < 4; ++i)
#pragma unroll
            for (int j = 0; j < 4; ++j)
                acc[i][j] = MFMA16(af[i], bfr[j], acc[i][j]);
    }

#pragma unroll
    for (int i = 0; i < 4; ++i) {
#pragma unroll
        for (int j = 0; j < 4; ++j) {
            const int col = n0 + wn + j * 16 + mrow;
#pragma unroll
            for (int r = 0; r < 4; ++r) {
                const int row = m0 + wm + i * 16 + quad * 4 + r;
                float v = acc[i][j][r];
                if (md == 4) {
                    v += bias3[row];
                    const int h = row >> 6, d = row & 63;
                    const int b = col >> 11, s = col & (SS - 1);
                    outvt[(((b * HH + h) * DD + d) * SS) + s] = (bf16)v;
                } else {
                    const int m2 = col >> 10;
                    const int cl = col & 1023;
                    const int h = cl >> 6, d = cl & 63;
                    const int b = row >> 11, s = row & (SS - 1);
                    v += (m2 ? bias2[cl] : bias[cl]);
                    v *= adapt[(b * HH + h) * DD + d];
                    // q: 1/sqrt(64) * log2(e) folded (attn uses exp2)
                    if (!m2) v *= 0.18033688011113811f;
                    outqk[(size_t)m2 * MM * EE + ((b * HH + h) * SS + s) * DD + d] = (bf16)v;
                }
            }
        }
    }
}

// ---------------------------------------------------------------------------
// Kernel 3: final GEMM (unchanged).
// ---------------------------------------------------------------------------
__global__ __launch_bounds__(256, 3) void gemm_o(
    const bf16* __restrict__ A, const bf16* __restrict__ Bt,
    const float* __restrict__ bias, float* __restrict__ outf) {
    __shared__ bf16 As[2 * 128 * 64];
    __shared__ bf16 Bs[2 * 64 * 64];

    const int t = threadIdx.x;
    const int w = t >> 6, lane = t & 63;
    const int mrow = lane & 15, quad = lane >> 4;
    const int m0 = blockIdx.x * 128, n0 = blockIdx.y * 64;

    f32x4 acc[2][4];
#pragma unroll
    for (int i = 0; i < 2; ++i)
#pragma unroll
        for (int j = 0; j < 4; ++j) acc[i][j] = zero4();

    const int grow = lane >> 3;
    const int gsw = ((lane & 7) ^ grow) * 8;
    const bf16* Ag = A + (size_t)(m0 + w * 32 + grow) * EE + gsw;
    const bf16* Bg = Bt + (size_t)(n0 + w * 16 + grow) * EE + gsw;
    bf16* Al = As + (w * 32) * 64;
    bf16* Bl = Bs + (w * 16) * 64;

#pragma unroll
    for (int i = 0; i < 4; ++i) gload16(Ag + i * 8 * EE, Al + i * 8 * 64);
#pragma unroll
    for (int i = 0; i < 2; ++i) gload16(Bg + i * 8 * EE, Bl + i * 8 * 64);

    for (int kt = 0; kt < 16; ++kt) {
        __syncthreads();
        if (kt < 15) {
            const int kn = (kt + 1) * 64;
            const int nb = (kt + 1) & 1;
#pragma unroll
            for (int i = 0; i < 4; ++i)
                gload16(Ag + i * 8 * EE + kn, Al + nb * 8192 + i * 8 * 64);
#pragma unroll
            for (int i = 0; i < 2; ++i)
                gload16(Bg + i * 8 * EE + kn, Bl + nb * 4096 + i * 8 * 64);
        }
        const bf16* Ab = As + (kt & 1) * 8192;
        const bf16* Bb = Bs + (kt & 1) * 4096;
#pragma unroll
        for (int ks = 0; ks < 2; ++ks) {
            const int cg = ks * 4 + quad;
            const int sw = (cg ^ (mrow & 7)) * 8;
            bf16x8 af[2], bfr[4];
#pragma unroll
            for (int mi = 0; mi < 2; ++mi)
                af[mi] = *(const bf16x8*)(Ab + (w * 32 + mi * 16 + mrow) * 64 + sw);
#pragma unroll
            for (int nj = 0; nj < 4; ++nj)
                bfr[nj] = *(const bf16x8*)(Bb + (nj * 16 + mrow) * 64 + sw);
#pragma unroll
            for (int mi = 0; mi < 2; ++mi)
#pragma unroll
                for (int nj = 0; nj < 4; ++nj)
                    acc[mi][nj] = MFMA16(af[mi], bfr[nj], acc[mi][nj]);
        }
    }

#pragma unroll
    for (int mi = 0; mi < 2; ++mi) {
#pragma unroll
        for (int nj = 0; nj < 4; ++nj) {
            const int col = n0 + nj * 16 + mrow;
#pragma unroll
            for (int r = 0; r < 4; ++r) {
                const int row = m0 + w * 32 + mi * 16 + quad * 4 + r;
                outf[row * EE + col] = acc[mi][nj][r] + bias[col];
            }
        }
    }
}

// ---------------------------------------------------------------------------
// Kernel 4: flash attention — R11 verified compute body, K-tile 128 staging.
// Each barrier stages 128 k-positions (Ks 128x64, Vs 64x128, dbuf = 64 KB);
// compute runs TWO 64-k phases (kh=0,1) per barrier -> 8 barriers/split
// instead of 16.  Registers unchanged (st/P32 reused per half).
// Split-K=2, 32x32 MFMA S^T formulation, register P^T, exp2 softmax.
// ---------------------------------------------------------------------------
__global__ __launch_bounds__(256, 2) void attn_kernel(
    const bf16* __restrict__ q, const bf16* __restrict__ k,
    const bf16* __restrict__ vt, bf16* __restrict__ o0, bf16* __restrict__ o1,
    float* __restrict__ lws) {
    __shared__ bf16 lds[32768];  // Ks[2][8192] | Vs[2][8192] = 64 KB;
                                 // epilogue reuses front as 4 x (64 x 66)
    bf16* Ks = lds;
    bf16* Vs = lds + 16384;

    const int t = threadIdx.x;
    const int w = t >> 6, lane = t & 63;
    const int q32 = lane & 31, h = lane >> 5;
    const int split = blockIdx.x >> 8;
    const int rest = blockIdx.x & 255;
    const int bh = rest >> 3;         // 0..31
    const int qb = rest & 7;          // 0..7 (256-row q tiles)
    const int qr0 = qb * 256 + w * 64;

    // Q B-frags: qi in {0,1} covers q-cols qr0 + qi*32 + q32
    bf16x8 qf[2][4];
#pragma unroll
    for (int qi = 0; qi < 2; ++qi)
#pragma unroll
        for (int c = 0; c < 4; ++c)
            qf[qi][c] = *(const bf16x8*)(q + (size_t)(bh * SS + qr0 + qi * 32 + q32) * DD +
                                         c * 16 + h * 8);

    f32x16 oacc[2][2];
#pragma unroll
    for (int qi = 0; qi < 2; ++qi)
#pragma unroll
        for (int mf = 0; mf < 2; ++mf)
#pragma unroll
            for (int i = 0; i < 16; ++i) oacc[qi][mf][i] = 0.f;
    float lsum[2] = {0.f, 0.f};

    // K DMA: instr covers 8 k-rows x 64 d; lane -> row +(lane>>3),
    // col-group (lane&7)^(lane>>3).  Wave w stages k-rows w*32 + i*8, i=0..3.
    const int kdr = lane >> 3;
    const int kdc = ((lane & 7) ^ kdr) * 8;
    // V DMA: instr covers 4 d-rows x 128 k; lane -> row +(lane>>4),
    // col-group (lane&15)^(row&15).  Wave w stages d-rows w*16 + i*4, i=0..3.
    const int vdr = lane >> 4;        // 0..3
    const int vlc = lane & 15;        // col-group pre-xor

    const bf16* kg = k + (size_t)bh * SS * DD;
    const bf16* vg = vt + (size_t)bh * DD * SS;

    const int ktbeg = split * 8, ktend = ktbeg + 8;  // tiles of 128 k-positions

    // prologue: stage tile ktbeg into buf 0 (ktbeg is even -> buf ktbeg&1 == 0)
#pragma unroll
    for (int i = 0; i < 4; ++i) {
        const int krb = w * 32 + i * 8;        // k-row base
        gload16(kg + (size_t)(ktbeg * 128 + krb + kdr) * DD + kdc, Ks + krb * 64);
        const int vrb = w * 16 + i * 4;        // d-row base
        gload16(vg + (size_t)(vrb + vdr) * SS + ktbeg * 128 + ((vlc ^ (i * 4 + vdr)) * 8),
                Vs + vrb * 128);
    }

    for (int kt = ktbeg; kt < ktend; ++kt) {
        __syncthreads();  // drains DMA for tile kt
        if (kt < ktend - 1) {
            const int nb = (kt + 1) & 1;
#pragma unroll
            for (int i = 0; i < 4; ++i) {
                const int krb = w * 32 + i * 8;
                gload16(kg + (size_t)((kt + 1) * 128 + krb + kdr) * DD + kdc,
                        Ks + nb * 8192 + krb * 64);
                const int vrb = w * 16 + i * 4;
                gload16(vg + (size_t)(vrb + vdr) * SS + (kt + 1) * 128 +
                        ((vlc ^ (i * 4 + vdr)) * 8),
                        Vs + nb * 8192 + vrb * 128);
            }
        }
        const bf16* Kb = Ks + (kt & 1) * 8192;
        const bf16* Vb = Vs + (kt & 1) * 8192;

#pragma unroll
        for (int kh = 0; kh < 2; ++kh) {
            const bf16* Kh = Kb + kh * 64 * 64;

            // ---- S^T = K·Q^T : 8 K-frag reads feed 16 MFMA (both qi) ----
            f32x16 st[2][2];
#pragma unroll
            for (int qi = 0; qi < 2; ++qi)
#pragma unroll
                for (int mf = 0; mf < 2; ++mf)
#pragma unroll
                    for (int i = 0; i < 16; ++i) st[qi][mf][i] = 0.f;
#pragma unroll
            for (int c = 0; c < 4; ++c) {
                const int sw = ((2 * c + h) ^ (q32 & 7)) * 8;
#pragma unroll
                for (int mf = 0; mf < 2; ++mf) {
                    bf16x8 kf = *(const bf16x8*)(Kh + (mf * 32 + q32) * 64 + sw);
#pragma unroll
                    for (int qi = 0; qi < 2; ++qi)
                        st[qi][mf] = MFMA32(kf, qf[qi][c], st[qi][mf]);
                }
            }

            // ---- p = exp2(s') (q carries log2e), pack ----
            u32 P32[2][2][8];
#pragma unroll
            for (int qi = 0; qi < 2; ++qi)
#pragma unroll
                for (int mf = 0; mf < 2; ++mf)
#pragma unroll
                    for (int rp = 0; rp < 8; ++rp) {
                        float pa = __builtin_amdgcn_exp2f(st[qi][mf][2 * rp]);
                        float pb = __builtin_amdgcn_exp2f(st[qi][mf][2 * rp + 1]);
                        lsum[qi] += pa + pb;
                        P32[qi][mf][rp] = pkbf(pa, pb);
                    }

            // ---- PV: 8 V-frag reads feed 16 MFMA (both qi) ----
#pragma unroll
            for (int c = 0; c < 4; ++c) {
                const int mfs = c >> 1;
                const int ro = (c & 1) * 4;
                union { u32 u[4]; bf16x8 v; } pb[2];
#pragma unroll
                for (int qi = 0; qi < 2; ++qi) {
                    u32 vA0 = P32[qi][mfs][ro + 0], vA1 = P32[qi][mfs][ro + 1];
                    u32 vB0 = P32[qi][mfs][ro + 2], vB1 = P32[qi][mfs][ro + 3];
                    u32 prep0 = h ? vA0 : vB0;
                    u32 prep1 = h ? vA1 : vB1;
                    u32 sh0 = __shfl_xor(prep0, 32);
                    u32 sh1 = __shfl_xor(prep1, 32);
                    pb[qi].u[0] = h ? sh0 : vA0;
                    pb[qi].u[1] = h ? sh1 : vA1;
                    pb[qi].u[2] = h ? vB0 : sh0;
                    pb[qi].u[3] = h ? vB1 : sh1;
                }
#pragma unroll
                for (int mf = 0; mf < 2; ++mf) {
                    const int vrow = mf * 32 + q32;  // d-row
                    const int sv = ((8 * kh + 2 * c + h) ^ (vrow & 15)) * 8;
                    bf16x8 vf = *(const bf16x8*)(Vb + vrow * 128 + sv);
#pragma unroll
                    for (int qi = 0; qi < 2; ++qi)
                        oacc[qi][mf] = MFMA32(vf, pb[qi].v, oacc[qi][mf]);
                }
            }
        }
    }

    lsum[0] += __shfl_xor(lsum[0], 32);
    lsum[1] += __shfl_xor(lsum[1], 32);

    // ---- epilogue: O^T regs -> per-wave LDS transpose -> coalesced store ----
    __syncthreads();  // all waves done with staging buffers
    bf16* ob = lds + w * 4224;  // 64 rows x stride 66
#pragma unroll
    for (int qi = 0; qi < 2; ++qi)
#pragma unroll
        for (int mf = 0; mf < 2; ++mf)
#pragma unroll
            for (int rp = 0; rp < 8; ++rp) {
                const int d = 32 * mf + 2 * (rp & 1) + 8 * (rp >> 1) + 4 * h;
                *(u32*)(ob + (qi * 32 + q32) * 66 + d) =
                    pkbf(oacc[qi][mf][2 * rp], oacc[qi][mf][2 * rp + 1]);
            }
    __builtin_amdgcn_s_waitcnt(0);

    bf16* op = split ? o1 : o0;
    const int b = bh >> 4, head = bh & 15;
    const int half = lane & 1;
#pragma unroll
    for (int p = 0; p < 2; ++p) {
        const int r = p * 32 + (lane >> 1);
#pragma unroll
        for (int i = 0; i < 4; ++i) {
            bf16x8 val = *(const bf16x8*)(ob + r * 66 + half * 32 + i * 8);
            *(bf16x8*)(op + (size_t)(b * SS + qr0 + r) * EE + head * DD +
                       half * 32 + i * 8) = val;
        }
    }
    if (lane < 32) {
#pragma unroll
        for (int qi = 0; qi < 2; ++qi)
            lws[split * (32 * SS) + bh * SS + qr0 + qi * 32 + q32] = lsum[qi];
    }
}

// ---------------------------------------------------------------------------
// Kernel 5: combine split-K partials: O = (p0 + p1) / (l0 + l1).
// ---------------------------------------------------------------------------
__global__ __launch_bounds__(256) void combine_kernel(
    const bf16* __restrict__ p1, const float* __restrict__ lws,
    bf16* __restrict__ o) {
    const int i = (blockIdx.x * 256 + threadIdx.x) * 8;
    const int b = i >> 21, s = (i >> 10) & (SS - 1), h = (i >> 6) & 15;
    const int li = (b * HH + h) * SS + s;
    const float inv = 1.f / (lws[li] + lws[32 * SS + li]);
    uint4 u0 = *(const uint4*)(o + i);
    uint4 u1 = *(const uint4*)(p1 + i);
    bf16 a0[8], a1[8], res[8];
    *(uint4*)a0 = u0; *(uint4*)a1 = u1;
#pragma unroll
    for (int j = 0; j < 8; ++j) res[j] = (bf16)(((float)a0[j] + (float)a1[j]) * inv);
    *(uint4*)(o + i) = *(uint4*)res;
}

// ---------------------------------------------------------------------------
extern "C" void kernel_launch(void* const* d_in, const int* in_sizes, int n_in,
                              void* d_out, int out_size, void* d_ws, size_t ws_size,
                              hipStream_t stream) {
    const float* query = (const float*)d_in[0];
    const float* xi    = (const float*)d_in[1];
    const float* Wq = (const float*)d_in[2];  const float* bq = (const float*)d_in[3];
    const float* Wk = (const float*)d_in[4];  const float* bk = (const float*)d_in[5];
    const float* Wv = (const float*)d_in[6];  const float* bv = (const float*)d_in[7];
    const float* Wo = (const float*)d_in[8];  const float* bo = (const float*)d_in[9];
    const float* ew1 = (const float*)d_in[10]; const float* eb1 = (const float*)d_in[11];
    const float* lng = (const float*)d_in[12]; const float* lnb = (const float*)d_in[13];
    const float* ew2 = (const float*)d_in[14]; const float* eb2 = (const float*)d_in[15];
    const float* gate = (const float*)d_in[16];
    float* out = (float*)d_out;

    char* ws = (char*)d_ws;
    const size_t SZ = (size_t)MM * EE * sizeof(bf16);  // 8 MB
    bf16* queryc = (bf16*)(ws);
    bf16* p0     = (bf16*)(ws);
    bf16* qws    = (bf16*)(ws + SZ);
    bf16* kws    = (bf16*)(ws + 2 * SZ);
    bf16* wqT    = (bf16*)(ws + 3 * SZ);
    bf16* wkT    = (bf16*)(ws + 3 * SZ + 2097152);
    bf16* wvT    = (bf16*)(ws + 3 * SZ + 2 * 2097152);
    bf16* woT    = (bf16*)(ws + 3 * SZ + 3 * 2097152);
    float* adaptws = (float*)(ws + 4 * SZ);
    float* lws   = (float*)(ws + 4 * SZ + 8192);
    bf16* vtws   = (bf16*)d_out;
    bf16* p1     = (bf16*)((char*)d_out + SZ);

    prep_kernel<<<3074, 256, 0, stream>>>(query, queryc, Wq, Wk, Wv, Wo,
                                          wqT, wkT, wvT, woT,
                                          xi, ew1, eb1, lng, lnb, ew2, eb2, gate,
                                          adaptws);

    // combined QK (512) + V^T (256) = 768 blocks = 3/CU
    gemm_qkv<<<768, 256, 0, stream>>>(queryc, wqT, wvT, bq, bk, bv, adaptws,
                                      qws, vtws);

    // 2 splits x 32 bh x 8 q-tiles = 512 blocks of 256 threads
    attn_kernel<<<512, 256, 0, stream>>>(qws, kws, vtws, p0, p1, lws);
    combine_kernel<<<MM * EE / (256 * 8), 256, 0, stream>>>(p1, lws, p0);

    gemm_o<<<dim3(MM / 128, EE / 64), 256, 0, stream>>>(p0, woT, bo, out);
}

// Round 16
// 216.670 us; speedup vs baseline: 1.0744x; 1.0744x over previous
//
#include <hip/hip_runtime.h>

typedef __bf16 bf16;
typedef __attribute__((ext_vector_type(8))) __bf16 bf16x8;
typedef __attribute__((ext_vector_type(4))) float f32x4;
typedef __attribute__((ext_vector_type(16))) float f32x16;
typedef unsigned int u32;

#define MFMA16(a, b, c) __builtin_amdgcn_mfma_f32_16x16x32_bf16((a), (b), (c), 0, 0, 0)
#define MFMA32(a, b, c) __builtin_amdgcn_mfma_f32_32x32x16_bf16((a), (b), (c), 0, 0, 0)

// Problem constants
#define BB 2
#define SS 2048
#define EE 1024
#define HH 16
#define DD 64
#define MM (BB * SS)  // 4096

__device__ inline f32x4 zero4() {
    f32x4 z; z.x = 0.f; z.y = 0.f; z.z = 0.f; z.w = 0.f; return z;
}

// async global->LDS DMA, 16B per lane.  LDS dest = wave-uniform base + lane*16.
__device__ __forceinline__ void gload16(const bf16* g, bf16* l) {
    __builtin_amdgcn_global_load_lds(
        (const __attribute__((address_space(1))) u32*)(const void*)g,
        (__attribute__((address_space(3))) u32*)(void*)l,
        16, 0, 0);
}

__device__ __forceinline__ u32 pkbf(float a, float b) {
    union { __bf16 h; unsigned short s; } ua, ub;
    ua.h = (__bf16)a; ub.h = (__bf16)b;
    return (u32)ua.s | ((u32)ub.s << 16);
}

// ---------------------------------------------------------------------------
// Kernel 1: fused prep.
// ---------------------------------------------------------------------------
__global__ __launch_bounds__(256) void prep_kernel(
    const float* __restrict__ query, bf16* __restrict__ qc,
    const float* __restrict__ s0, const float* __restrict__ s1,
    const float* __restrict__ s2, const float* __restrict__ s3,
    bf16* __restrict__ d0, bf16* __restrict__ d1,
    bf16* __restrict__ d2, bf16* __restrict__ d3,
    const float* __restrict__ xi, const float* __restrict__ w1,
    const float* __restrict__ b1, const float* __restrict__ lng,
    const float* __restrict__ lnb, const float* __restrict__ w2,
    const float* __restrict__ b2, const float* __restrict__ gate,
    float* __restrict__ adapt) {
    __shared__ bf16 tile[64 * 72];
    const int bid = blockIdx.x;
    const int t = threadIdx.x;

    if (bid < 2048) {
        const int i = (bid * 256 + t) * 8;
        float4 a = *(const float4*)(query + i);
        float4 b = *(const float4*)(query + i + 4);
        bf16 tmp[8];
        tmp[0] = (bf16)a.x; tmp[1] = (bf16)a.y; tmp[2] = (bf16)a.z; tmp[3] = (bf16)a.w;
        tmp[4] = (bf16)b.x; tmp[5] = (bf16)b.y; tmp[6] = (bf16)b.z; tmp[7] = (bf16)b.w;
        *(uint4*)(qc + i) = *(uint4*)tmp;
    } else if (bid < 3072) {
        const int m = (bid - 2048) >> 8;
        const int idx0 = (bid - 2048) & 255;
        const float* W = (m == 0) ? s0 : (m == 1) ? s1 : (m == 2) ? s2 : s3;
        bf16* Wt = (m == 0) ? d0 : (m == 1) ? d1 : (m == 2) ? d2 : d3;
        const int k0 = (idx0 >> 4) * 64, n0 = (idx0 & 15) * 64;
#pragma unroll
        for (int i = 0; i < 2; ++i) {
            int idx = i * 256 + t;
            int r = idx >> 3, c = (idx & 7) * 8;
            float4 a = *(const float4*)(W + (k0 + r) * EE + n0 + c);
            float4 b = *(const float4*)(W + (k0 + r) * EE + n0 + c + 4);
            bf16 tmp[8];
            tmp[0] = (bf16)a.x; tmp[1] = (bf16)a.y; tmp[2] = (bf16)a.z; tmp[3] = (bf16)a.w;
            tmp[4] = (bf16)b.x; tmp[5] = (bf16)b.y; tmp[6] = (bf16)b.z; tmp[7] = (bf16)b.w;
            *(uint4*)(tile + r * 72 + c) = *(uint4*)tmp;
        }
        __syncthreads();
#pragma unroll
        for (int i = 0; i < 2; ++i) {
            int idx = i * 256 + t;
            int n = idx >> 3, kc = (idx & 7) * 8;
            bf16 tmp[8];
#pragma unroll
            for (int j = 0; j < 8; ++j) tmp[j] = tile[(kc + j) * 72 + n];
            *(uint4*)(Wt + (n0 + n) * EE + k0 + kc) = *(uint4*)tmp;
        }
    } else {
        const int b = bid - 3072;
        float* xs = (float*)tile;
        if (t < 64) {
            const float xiv = xi[b];
            float xv = 0.f;
            if (t < 32) xv = xiv * w1[t] + b1[t];
            float sm = xv;
            for (int off = 1; off < 32; off <<= 1) sm += __shfl_xor(sm, off);
            const float mu = sm * (1.f / 32.f);
            float dv = (t < 32) ? (xv - mu) : 0.f;
            float s2 = dv * dv;
            for (int off = 1; off < 32; off <<= 1) s2 += __shfl_xor(s2, off);
            const float var = s2 * (1.f / 32.f);
            if (t < 32) {
                float xn = (xv - mu) * rsqrtf(var + 1e-5f) * lng[t] + lnb[t];
                float ge = 0.5f * xn * (1.f + erff(xn * 0.70710678118654752f));
                xs[t] = ge;
            }
        }
        __syncthreads();
        if (t < 64) {
            float acc = b2[t];
            for (int j = 0; j < 32; ++j) acc += xs[j] * w2[j * DD + t];
            for (int h = 0; h < HH; ++h) {
                float sg = 1.f / (1.f + __expf(-gate[h]));
                adapt[(b * HH + h) * DD + t] = 1.f + sg * acc;
            }
        }
    }
}

// ---------------------------------------------------------------------------
// Kernel 2: QKV GEMM — 128x128 tile, BK=32, dbuf DMA, one barrier/iter.
// q-scale folds 0.125*log2(e) so attention uses bare v_exp_f32 (exp2).
// ---------------------------------------------------------------------------
__global__ __launch_bounds__(256, 3) void gemm_qkv(
    const bf16* __restrict__ Aq, const bf16* __restrict__ Bqk,
    const bf16* __restrict__ Av,
    const float* __restrict__ bias, const float* __restrict__ bias2,
    const float* __restrict__ bias3, const float* __restrict__ adapt,
    bf16* __restrict__ outqk, bf16* __restrict__ outvt) {
    __shared__ bf16 As[2 * 128 * 32];
    __shared__ bf16 Bs[2 * 128 * 32];

    const int t = threadIdx.x;
    const int w = t >> 6, lane = t & 63;
    const int mrow = lane & 15, quad = lane >> 4;
    const int wm = (w & 1) * 64, wn = (w >> 1) * 64;

    int md, bx, by;
    const bf16 *Ap, *Bp;
    int bid = blockIdx.x;
    if (bid < 512) { md = 5; bx = bid & 31; by = bid >> 5; Ap = Aq; Bp = Bqk; }
    else { md = 4; bid -= 512; bx = bid & 7; by = bid >> 3; Ap = Av; Bp = Aq; }
    const int m0 = bx * 128, n0 = by * 128;

    f32x4 acc[4][4];
#pragma unroll
    for (int i = 0; i < 4; ++i)
#pragma unroll
        for (int j = 0; j < 4; ++j) acc[i][j] = zero4();

    const int dr = lane >> 2;
    const int dcg = ((lane & 3) ^ (dr & 3)) * 8;
    const bf16* Ag = Ap + (size_t)(m0 + w * 16 + dr) * EE + dcg;
    const bf16* Bg = Bp + (size_t)(n0 + w * 16 + dr) * EE + dcg;
    bf16* Al = As + (w * 16) * 32;
    bf16* Bl = Bs + (w * 16) * 32;

    gload16(Ag, Al);
    gload16(Ag + 64 * EE, Al + 64 * 32);
    gload16(Bg, Bl);
    gload16(Bg + 64 * EE, Bl + 64 * 32);

    for (int kt = 0; kt < 32; ++kt) {
        __syncthreads();
        if (kt < 31) {
            const int kn = (kt + 1) * 32;
            const int nb = (kt + 1) & 1;
            gload16(Ag + kn, Al + nb * 4096);
            gload16(Ag + 64 * EE + kn, Al + nb * 4096 + 64 * 32);
            gload16(Bg + kn, Bl + nb * 4096);
            gload16(Bg + 64 * EE + kn, Bl + nb * 4096 + 64 * 32);
        }
        const bf16* Ab = As + (kt & 1) * 4096;
        const bf16* Bb = Bs + (kt & 1) * 4096;
        const int sw = (quad ^ (mrow & 3)) * 8;
        bf16x8 af[4], bfr[4];
#pragma unroll
        for (int i = 0; i < 4; ++i)
            af[i] = *(const bf16x8*)(Ab + (wm + i * 16 + mrow) * 32 + sw);
#pragma unroll
        for (int j = 0; j < 4; ++j)
            bfr[j] = *(const bf16x8*)(Bb + (wn + j * 16 + mrow) * 32 + sw);
#pragma unroll
        for (int i = 0; i < 4; ++i)
#pragma unroll
            for (int j = 0; j < 4; ++j)
                acc[i][j] = MFMA16(af[i], bfr[j], acc[i][j]);
    }

#pragma unroll
    for (int i = 0; i < 4; ++i) {
#pragma unroll
        for (int j = 0; j < 4; ++j) {
            const int col = n0 + wn + j * 16 + mrow;
#pragma unroll
            for (int r = 0; r < 4; ++r) {
                const int row = m0 + wm + i * 16 + quad * 4 + r;
                float v = acc[i][j][r];
                if (md == 4) {
                    v += bias3[row];
                    const int h = row >> 6, d = row & 63;
                    const int b = col >> 11, s = col & (SS - 1);
                    outvt[(((b * HH + h) * DD + d) * SS) + s] = (bf16)v;
                } else {
                    const int m2 = col >> 10;
                    const int cl = col & 1023;
                    const int h = cl >> 6, d = cl & 63;
                    const int b = row >> 11, s = row & (SS - 1);
                    v += (m2 ? bias2[cl] : bias[cl]);
                    v *= adapt[(b * HH + h) * DD + d];
                    // q: 1/sqrt(64) * log2(e) folded (attn uses exp2)
                    if (!m2) v *= 0.18033688011113811f;
                    outqk[(size_t)m2 * MM * EE + ((b * HH + h) * SS + s) * DD + d] = (bf16)v;
                }
            }
        }
    }
}

// ---------------------------------------------------------------------------
// Kernel 3: final GEMM.
// ---------------------------------------------------------------------------
__global__ __launch_bounds__(256, 3) void gemm_o(
    const bf16* __restrict__ A, const bf16* __restrict__ Bt,
    const float* __restrict__ bias, float* __restrict__ outf) {
    __shared__ bf16 As[2 * 128 * 64];
    __shared__ bf16 Bs[2 * 64 * 64];

    const int t = threadIdx.x;
    const int w = t >> 6, lane = t & 63;
    const int mrow = lane & 15, quad = lane >> 4;
    const int m0 = blockIdx.x * 128, n0 = blockIdx.y * 64;

    f32x4 acc[2][4];
#pragma unroll
    for (int i = 0; i < 2; ++i)
#pragma unroll
        for (int j = 0; j < 4; ++j) acc[i][j] = zero4();

    const int grow = lane >> 3;
    const int gsw = ((lane & 7) ^ grow) * 8;
    const bf16* Ag = A + (size_t)(m0 + w * 32 + grow) * EE + gsw;
    const bf16* Bg = Bt + (size_t)(n0 + w * 16 + grow) * EE + gsw;
    bf16* Al = As + (w * 32) * 64;
    bf16* Bl = Bs + (w * 16) * 64;

#pragma unroll
    for (int i = 0; i < 4; ++i) gload16(Ag + i * 8 * EE, Al + i * 8 * 64);
#pragma unroll
    for (int i = 0; i < 2; ++i) gload16(Bg + i * 8 * EE, Bl + i * 8 * 64);

    for (int kt = 0; kt < 16; ++kt) {
        __syncthreads();
        if (kt < 15) {
            const int kn = (kt + 1) * 64;
            const int nb = (kt + 1) & 1;
#pragma unroll
            for (int i = 0; i < 4; ++i)
                gload16(Ag + i * 8 * EE + kn, Al + nb * 8192 + i * 8 * 64);
#pragma unroll
            for (int i = 0; i < 2; ++i)
                gload16(Bg + i * 8 * EE + kn, Bl + nb * 4096 + i * 8 * 64);
        }
        const bf16* Ab = As + (kt & 1) * 8192;
        const bf16* Bb = Bs + (kt & 1) * 4096;
#pragma unroll
        for (int ks = 0; ks < 2; ++ks) {
            const int cg = ks * 4 + quad;
            const int sw = (cg ^ (mrow & 7)) * 8;
            bf16x8 af[2], bfr[4];
#pragma unroll
            for (int mi = 0; mi < 2; ++mi)
                af[mi] = *(const bf16x8*)(Ab + (w * 32 + mi * 16 + mrow) * 64 + sw);
#pragma unroll
            for (int nj = 0; nj < 4; ++nj)
                bfr[nj] = *(const bf16x8*)(Bb + (nj * 16 + mrow) * 64 + sw);
#pragma unroll
            for (int mi = 0; mi < 2; ++mi)
#pragma unroll
                for (int nj = 0; nj < 4; ++nj)
                    acc[mi][nj] = MFMA16(af[mi], bfr[nj], acc[mi][nj]);
        }
    }

#pragma unroll
    for (int mi = 0; mi < 2; ++mi) {
#pragma unroll
        for (int nj = 0; nj < 4; ++nj) {
            const int col = n0 + nj * 16 + mrow;
#pragma unroll
            for (int r = 0; r < 4; ++r) {
                const int row = m0 + w * 32 + mi * 16 + quad * 4 + r;
                outf[row * EE + col] = acc[mi][nj][r] + bias[col];
            }
        }
    }
}

// ---------------------------------------------------------------------------
// Kernel 4: flash attention (R11/R14 known-good: split-K=2, 32x32 MFMA, S^T
// formulation, register P^T, wide waves 64 q-cols/wave, K-tile 64, dbuf DMA,
// one barrier/iter, exp2 softmax).  Block = 256 q rows; grid 512.
// NOTE: measured dead ends — do not re-attempt: split-K=4 (R12/R13,
// timing-sensitive failure), K-tile 32 (R10, partial-line HBM blowup),
// K-tile 128 (R15, drain volume conserved + spill), launch_bounds (256,4)
// (R12, VGPR 64 forced -> 1 GB scratch spill).
// ---------------------------------------------------------------------------
__global__ __launch_bounds__(256, 2) void attn_kernel(
    const bf16* __restrict__ q, const bf16* __restrict__ k,
    const bf16* __restrict__ vt, bf16* __restrict__ o0, bf16* __restrict__ o1,
    float* __restrict__ lws) {
    __shared__ bf16 lds[16896];  // staging: Ks[2][4096] | Vs[2][4096] (16384);
                                 // epilogue reuses as 4 x (64 x 66)
    bf16* Ks = lds;
    bf16* Vs = lds + 8192;

    const int t = threadIdx.x;
    const int w = t >> 6, lane = t & 63;
    const int q32 = lane & 31, h = lane >> 5;
    const int split = blockIdx.x >> 8;
    const int rest = blockIdx.x & 255;
    const int bh = rest >> 3;         // 0..31
    const int qb = rest & 7;          // 0..7 (256-row q tiles)
    const int qr0 = qb * 256 + w * 64;

    // Q B-frags: qi in {0,1} covers q-cols qr0 + qi*32 + q32
    bf16x8 qf[2][4];
#pragma unroll
    for (int qi = 0; qi < 2; ++qi)
#pragma unroll
        for (int c = 0; c < 4; ++c)
            qf[qi][c] = *(const bf16x8*)(q + (size_t)(bh * SS + qr0 + qi * 32 + q32) * DD +
                                         c * 16 + h * 8);

    f32x16 oacc[2][2];
#pragma unroll
    for (int qi = 0; qi < 2; ++qi)
#pragma unroll
        for (int mf = 0; mf < 2; ++mf)
#pragma unroll
            for (int i = 0; i < 16; ++i) oacc[qi][mf][i] = 0.f;
    float lsum[2] = {0.f, 0.f};

    const int dr = lane >> 3;
    const int dcg = ((lane & 7) ^ dr) * 8;
    const bf16* kg = k + (size_t)bh * SS * DD;
    const bf16* vg = vt + (size_t)bh * DD * SS;
    const bf16* kgl = kg + (size_t)dr * DD + dcg;
    const bf16* vgl = vg + (size_t)(w * 16 + dr) * SS + dcg;

    const int ktbeg = split * (SS / 128), ktend = ktbeg + (SS / 128);

#pragma unroll
    for (int i = 0; i < 2; ++i) {
        const int rb = w * 16 + i * 8;
        gload16(kgl + (size_t)(ktbeg * 64 + rb) * DD, Ks + rb * 64);
        gload16(vgl + (size_t)(i * 8) * SS + ktbeg * 64, Vs + rb * 64);
    }

    for (int kt = ktbeg; kt < ktend; ++kt) {
        __syncthreads();
        if (kt < ktend - 1) {
            const int nb = (kt + 1) & 1;
#pragma unroll
            for (int i = 0; i < 2; ++i) {
                const int rb = w * 16 + i * 8;
                gload16(kgl + (size_t)((kt + 1) * 64 + rb) * DD, Ks + nb * 4096 + rb * 64);
                gload16(vgl + (size_t)(i * 8) * SS + (kt + 1) * 64, Vs + nb * 4096 + rb * 64);
            }
        }
        const bf16* Kb = Ks + (kt & 1) * 4096;
        const bf16* Vb = Vs + (kt & 1) * 4096;

        // ---- S^T = K·Q^T : 8 K-frag reads feed 16 MFMA (both qi) ----
        f32x16 st[2][2];
#pragma unroll
        for (int qi = 0; qi < 2; ++qi)
#pragma unroll
            for (int mf = 0; mf < 2; ++mf)
#pragma unroll
                for (int i = 0; i < 16; ++i) st[qi][mf][i] = 0.f;
#pragma unroll
        for (int c = 0; c < 4; ++c) {
            const int sw = ((2 * c + h) ^ (q32 & 7)) * 8;
#pragma unroll
            for (int mf = 0; mf < 2; ++mf) {
                bf16x8 kf = *(const bf16x8*)(Kb + (mf * 32 + q32) * 64 + sw);
#pragma unroll
                for (int qi = 0; qi < 2; ++qi)
                    st[qi][mf] = MFMA32(kf, qf[qi][c], st[qi][mf]);
            }
        }

        // ---- p = exp2(s') (q carries log2e), pack ----
        u32 P32[2][2][8];
#pragma unroll
        for (int qi = 0; qi < 2; ++qi)
#pragma unroll
            for (int mf = 0; mf < 2; ++mf)
#pragma unroll
                for (int rp = 0; rp < 8; ++rp) {
                    float pa = __builtin_amdgcn_exp2f(st[qi][mf][2 * rp]);
                    float pb = __builtin_amdgcn_exp2f(st[qi][mf][2 * rp + 1]);
                    lsum[qi] += pa + pb;
                    P32[qi][mf][rp] = pkbf(pa, pb);
                }

        // ---- PV: 8 V-frag reads feed 16 MFMA (both qi) ----
#pragma unroll
        for (int c = 0; c < 4; ++c) {
            const int mfs = c >> 1;
            const int ro = (c & 1) * 4;
            union { u32 u[4]; bf16x8 v; } pb[2];
#pragma unroll
            for (int qi = 0; qi < 2; ++qi) {
                u32 vA0 = P32[qi][mfs][ro + 0], vA1 = P32[qi][mfs][ro + 1];
                u32 vB0 = P32[qi][mfs][ro + 2], vB1 = P32[qi][mfs][ro + 3];
                u32 prep0 = h ? vA0 : vB0;
                u32 prep1 = h ? vA1 : vB1;
                u32 sh0 = __shfl_xor(prep0, 32);
                u32 sh1 = __shfl_xor(prep1, 32);
                pb[qi].u[0] = h ? sh0 : vA0;
                pb[qi].u[1] = h ? sh1 : vA1;
                pb[qi].u[2] = h ? vB0 : sh0;
                pb[qi].u[3] = h ? vB1 : sh1;
            }
            const int sw = ((2 * c + h) ^ (q32 & 7)) * 8;
#pragma unroll
            for (int mf = 0; mf < 2; ++mf) {
                bf16x8 vf = *(const bf16x8*)(Vb + (mf * 32 + q32) * 64 + sw);
#pragma unroll
                for (int qi = 0; qi < 2; ++qi)
                    oacc[qi][mf] = MFMA32(vf, pb[qi].v, oacc[qi][mf]);
            }
        }
    }

    lsum[0] += __shfl_xor(lsum[0], 32);
    lsum[1] += __shfl_xor(lsum[1], 32);

    // ---- epilogue: O^T regs -> per-wave LDS transpose -> coalesced store ----
    __syncthreads();  // all waves done with staging buffers
    bf16* ob = lds + w * 4224;  // 64 rows x stride 66
#pragma unroll
    for (int qi = 0; qi < 2; ++qi)
#pragma unroll
        for (int mf = 0; mf < 2; ++mf)
#pragma unroll
            for (int rp = 0; rp < 8; ++rp) {
                const int d = 32 * mf + 2 * (rp & 1) + 8 * (rp >> 1) + 4 * h;
                *(u32*)(ob + (qi * 32 + q32) * 66 + d) =
                    pkbf(oacc[qi][mf][2 * rp], oacc[qi][mf][2 * rp + 1]);
            }
    __builtin_amdgcn_s_waitcnt(0);

    bf16* op = split ? o1 : o0;
    const int b = bh >> 4, head = bh & 15;
    const int half = lane & 1;
#pragma unroll
    for (int p = 0; p < 2; ++p) {
        const int r = p * 32 + (lane >> 1);
#pragma unroll
        for (int i = 0; i < 4; ++i) {
            bf16x8 val = *(const bf16x8*)(ob + r * 66 + half * 32 + i * 8);
            *(bf16x8*)(op + (size_t)(b * SS + qr0 + r) * EE + head * DD +
                       half * 32 + i * 8) = val;
        }
    }
    if (lane < 32) {
#pragma unroll
        for (int qi = 0; qi < 2; ++qi)
            lws[split * (32 * SS) + bh * SS + qr0 + qi * 32 + q32] = lsum[qi];
    }
}

// ---------------------------------------------------------------------------
// Kernel 5: combine split-K partials: O = (p0 + p1) / (l0 + l1).
// ---------------------------------------------------------------------------
__global__ __launch_bounds__(256) void combine_kernel(
    const bf16* __restrict__ p1, const float* __restrict__ lws,
    bf16* __restrict__ o) {
    const int i = (blockIdx.x * 256 + threadIdx.x) * 8;
    const int b = i >> 21, s = (i >> 10) & (SS - 1), h = (i >> 6) & 15;
    const int li = (b * HH + h) * SS + s;
    const float inv = 1.f / (lws[li] + lws[32 * SS + li]);
    uint4 u0 = *(const uint4*)(o + i);
    uint4 u1 = *(const uint4*)(p1 + i);
    bf16 a0[8], a1[8], res[8];
    *(uint4*)a0 = u0; *(uint4*)a1 = u1;
#pragma unroll
    for (int j = 0; j < 8; ++j) res[j] = (bf16)(((float)a0[j] + (float)a1[j]) * inv);
    *(uint4*)(o + i) = *(uint4*)res;
}

// ---------------------------------------------------------------------------
extern "C" void kernel_launch(void* const* d_in, const int* in_sizes, int n_in,
                              void* d_out, int out_size, void* d_ws, size_t ws_size,
                              hipStream_t stream) {
    const float* query = (const float*)d_in[0];
    const float* xi    = (const float*)d_in[1];
    const float* Wq = (const float*)d_in[2];  const float* bq = (const float*)d_in[3];
    const float* Wk = (const float*)d_in[4];  const float* bk = (const float*)d_in[5];
    const float* Wv = (const float*)d_in[6];  const float* bv = (const float*)d_in[7];
    const float* Wo = (const float*)d_in[8];  const float* bo = (const float*)d_in[9];
    const float* ew1 = (const float*)d_in[10]; const float* eb1 = (const float*)d_in[11];
    const float* lng = (const float*)d_in[12]; const float* lnb = (const float*)d_in[13];
    const float* ew2 = (const float*)d_in[14]; const float* eb2 = (const float*)d_in[15];
    const float* gate = (const float*)d_in[16];
    float* out = (float*)d_out;

    char* ws = (char*)d_ws;
    const size_t SZ = (size_t)MM * EE * sizeof(bf16);  // 8 MB
    bf16* queryc = (bf16*)(ws);
    bf16* p0     = (bf16*)(ws);
    bf16* qws    = (bf16*)(ws + SZ);
    bf16* kws    = (bf16*)(ws + 2 * SZ);
    bf16* wqT    = (bf16*)(ws + 3 * SZ);
    bf16* wkT    = (bf16*)(ws + 3 * SZ + 2097152);
    bf16* wvT    = (bf16*)(ws + 3 * SZ + 2 * 2097152);
    bf16* woT    = (bf16*)(ws + 3 * SZ + 3 * 2097152);
    float* adaptws = (float*)(ws + 4 * SZ);
    float* lws   = (float*)(ws + 4 * SZ + 8192);
    bf16* vtws   = (bf16*)d_out;
    bf16* p1     = (bf16*)((char*)d_out + SZ);

    prep_kernel<<<3074, 256, 0, stream>>>(query, queryc, Wq, Wk, Wv, Wo,
                                          wqT, wkT, wvT, woT,
                                          xi, ew1, eb1, lng, lnb, ew2, eb2, gate,
                                          adaptws);

    // combined QK (512) + V^T (256) = 768 blocks = 3/CU
    gemm_qkv<<<768, 256, 0, stream>>>(queryc, wqT, wvT, bq, bk, bv, adaptws,
                                      qws, vtws);

    // 2 splits x 32 bh x 8 q-tiles = 512 blocks of 256 threads
    attn_kernel<<<512, 256, 0, stream>>>(qws, kws, vtws, p0, p1, lws);
    combine_kernel<<<MM * EE / (256 * 8), 256, 0, stream>>>(p1, lws, p0);

    gemm_o<<<dim3(MM / 128, EE / 64), 256, 0, stream>>>(p0, woT, bo, out);
}